// Round 2
// baseline (347.342 us; speedup 1.0000x reference)
//
#include <hip/hip_runtime.h>
#include <math.h>

#define EPS_AREA 1e-6f
#define EPS_BCE  1e-7f

typedef float v4f __attribute__((ext_vector_type(4)));

// Kernel 1: features_poses[row, :, :] = pred_poses_flat[row], row = l*3K + j.
// One row per WAVE (4 rows per 256-thread block), plain temporal float4
// stores (NT stores measured ~6x slower: they bypass L2 write-coalescing).
__global__ __launch_bounds__(256) void broadcast_kernel(
    const float* __restrict__ pred, float* __restrict__ out,
    int rows, long inner, int inner4)
{
    const int wave = threadIdx.x >> 6;
    const int lane = threadIdx.x & 63;
    const int row  = blockIdx.x * 4 + wave;
    if (row >= rows) return;

    const float v = pred[row];            // wave-uniform -> scalar load
    v4f val;
    val.x = v; val.y = v; val.z = v; val.w = v;

    float* rowp = out + (size_t)row * (size_t)inner;
    v4f* dst = (v4f*)rowp;
    for (int i = lane; i < inner4; i += 64)
        dst[i] = val;                     // 12-13 coalesced 16B stores/lane

    const int rem = (int)(inner - (long)inner4 * 4);
    if (rem && lane < rem)                // not taken for fd=56
        rowp[(size_t)inner4 * 4 + lane] = v;
}

// Kernel 2 (stage 1): partial[l] = sum_lp ious[l,lp]*(feedback_loss + bce).
// One block per l; 64 threads = 1 wave; lane = lp. NO atomics.
__global__ __launch_bounds__(64) void loss_partial_kernel(
    const float* __restrict__ pred_poses,     // (L,K,3)
    const float* __restrict__ target_poses,   // (Lp,K,3)
    const float* __restrict__ pred_feedbacks, // (L,)
    const float* __restrict__ ious,           // (L,Lp)
    const float* __restrict__ target_areas,   // (Lp,)
    float* __restrict__ partial,              // (L,) in d_ws
    int Lp, int K)
{
    extern __shared__ float sm[];             // px[K], py[K], lpv[K], l1m[K]
    float* px  = sm;
    float* py  = sm + K;
    float* lpv = sm + 2 * K;
    float* l1m = sm + 3 * K;

    const int l   = blockIdx.x;
    const int tid = threadIdx.x;

    if (tid < K) {
        const float* p = pred_poses + ((size_t)l * K + tid) * 3;
        px[tid] = p[0];
        py[tid] = p[1];
        float pv = fminf(fmaxf(p[2], EPS_BCE), 1.0f - EPS_BCE);
        lpv[tid] = logf(pv);
        l1m[tid] = logf(1.0f - pv);
    }
    __syncthreads();

    float acc = 0.0f;
    for (int lp = tid; lp < Lp; lp += 64) {
        const float  invDen = 1.0f / (2.0f * target_areas[lp] + EPS_AREA);
        const float* t = target_poses + (size_t)lp * K * 3;
        float sumExp = 0.0f;
        float sBce   = 0.0f;
        for (int k = 0; k < K; ++k) {
            float tx = t[3 * k + 0];
            float ty = t[3 * k + 1];
            float tv = t[3 * k + 2];
            float dx = px[k] - tx;
            float dy = py[k] - ty;
            float d2 = dx * dx + dy * dy;
            sumExp += expf(-d2 * invDen);
            sBce   += tv * lpv[k] + (1.0f - tv) * l1m[k];
        }
        float tf  = sumExp / (float)K;
        float d   = pred_feedbacks[l] - tf;
        acc += ious[(size_t)l * Lp + lp] * (d * d - sBce / (float)K);
    }

    for (int off = 32; off > 0; off >>= 1)
        acc += __shfl_down(acc, off, 64);
    if (tid == 0)
        partial[l] = acc;
}

// Kernel 3 (stage 2): single block reduces partial[0..L) -> loss slot.
__global__ __launch_bounds__(256) void loss_reduce_kernel(
    const float* __restrict__ partial, float* __restrict__ loss_out, int L)
{
    __shared__ float wsum[4];
    float s = 0.0f;
    for (int i = threadIdx.x; i < L; i += 256)
        s += partial[i];
    for (int off = 32; off > 0; off >>= 1)
        s += __shfl_down(s, off, 64);
    const int wave = threadIdx.x >> 6;
    const int lane = threadIdx.x & 63;
    if (lane == 0) wsum[wave] = s;
    __syncthreads();
    if (threadIdx.x == 0)
        *loss_out = wsum[0] + wsum[1] + wsum[2] + wsum[3];
}

extern "C" void kernel_launch(void* const* d_in, const int* in_sizes, int n_in,
                              void* d_out, int out_size, void* d_ws, size_t ws_size,
                              hipStream_t stream) {
    const float* pred_poses     = (const float*)d_in[0];  // (L,K,3)
    const float* target_poses   = (const float*)d_in[1];  // (Lp,K,3)
    const float* pred_feedbacks = (const float*)d_in[2];  // (L,)
    const float* ious           = (const float*)d_in[3];  // (L,Lp)
    const float* target_areas   = (const float*)d_in[4];  // (Lp,)
    float* out = (float*)d_out;

    const int L  = in_sizes[2];                 // 512
    const int Lp = in_sizes[4];                 // 64
    const int K  = in_sizes[0] / (3 * L);       // 17

    const long rows  = (long)L * 3 * K;                   // 26112
    const long inner = ((long)out_size - 1) / rows;       // fd*fd = 3136
    const int  inner4 = (int)(inner / 4);                 // 784

    float* loss_slot = out + ((size_t)out_size - 1);
    float* partial   = (float*)d_ws;                      // L floats

    broadcast_kernel<<<(int)((rows + 3) / 4), 256, 0, stream>>>(
        pred_poses, out, (int)rows, inner, inner4);

    const size_t smem = 4 * (size_t)K * sizeof(float);
    loss_partial_kernel<<<L, 64, smem, stream>>>(
        pred_poses, target_poses, pred_feedbacks, ious, target_areas,
        partial, Lp, K);

    loss_reduce_kernel<<<1, 256, 0, stream>>>(partial, loss_slot, L);
}

// Round 3
// 335.909 us; speedup vs baseline: 1.0340x; 1.0340x over previous
//
#include <hip/hip_runtime.h>
#include <math.h>

#define EPS_AREA 1e-6f
#define EPS_BCE  1e-7f

typedef float v4f __attribute__((ext_vector_type(4)));

// ---------------------------------------------------------------------------
// Fast-path broadcast: flat grid-stride float4 stores over the whole output
// (same access pattern as the rocclr fill that sustains 6.25 TB/s on this
// buffer). row = float4_idx / INNER4 with INNER4 compile-time -> magic div.
// Block 0 / wave 0 also reduces the per-l loss partials (produced by the
// preceding loss kernel) into the final loss slot.
// ---------------------------------------------------------------------------
template <int INNER4>
__global__ __launch_bounds__(256) void broadcast_flat_kernel(
    const float* __restrict__ pred, float* __restrict__ out,
    unsigned int total4,
    const float* __restrict__ partial, float* __restrict__ loss_out, int L)
{
    if (blockIdx.x == 0 && threadIdx.x < 64) {
        float s = 0.0f;
        for (int i = threadIdx.x; i < L; i += 64) s += partial[i];
        for (int off = 32; off > 0; off >>= 1) s += __shfl_down(s, off, 64);
        if (threadIdx.x == 0) *loss_out = s;
    }

    v4f* dst = (v4f*)out;
    const unsigned int stride = gridDim.x * blockDim.x;
    for (unsigned int i = blockIdx.x * blockDim.x + threadIdx.x; i < total4;
         i += stride) {
        const unsigned int row = i / (unsigned int)INNER4;  // magic div
        const float v = pred[row];
        v4f val;
        val.x = v; val.y = v; val.z = v; val.w = v;
        dst[i] = val;
    }
}

// Generic fallback broadcast (any inner): one row per wave.
__global__ __launch_bounds__(256) void broadcast_rows_kernel(
    const float* __restrict__ pred, float* __restrict__ out,
    int rows, long inner, int inner4)
{
    const int wave = threadIdx.x >> 6;
    const int lane = threadIdx.x & 63;
    const int row  = blockIdx.x * 4 + wave;
    if (row >= rows) return;
    const float v = pred[row];
    v4f val;
    val.x = v; val.y = v; val.z = v; val.w = v;
    float* rowp = out + (size_t)row * (size_t)inner;
    v4f* dst = (v4f*)rowp;
    for (int i = lane; i < inner4; i += 64) dst[i] = val;
    const int rem = (int)(inner - (long)inner4 * 4);
    if (rem && lane < rem) rowp[(size_t)inner4 * 4 + lane] = v;
}

// ---------------------------------------------------------------------------
// Loss stage 1 (fast path, Lp <= 64): one block per l, 256 threads = 4 waves.
// Wave w handles k = w, w+4, ... ; lane = lp. Per-(lp) partial sums combined
// through LDS, wave 0 applies the nonlinearity and butterfly-reduces over lp.
// partial[l] -> d_ws.  No atomics.
// ---------------------------------------------------------------------------
__global__ __launch_bounds__(256) void loss_partial4_kernel(
    const float* __restrict__ pred_poses,     // (L,K,3)
    const float* __restrict__ target_poses,   // (Lp,K,3)
    const float* __restrict__ pred_feedbacks, // (L,)
    const float* __restrict__ ious,           // (L,Lp)
    const float* __restrict__ target_areas,   // (Lp,)
    float* __restrict__ partial,              // (L,)
    int Lp, int K)
{
    extern __shared__ float sm[];  // px[K] py[K] lpv[K] l1m[K] red[512]
    float* px  = sm;
    float* py  = sm + K;
    float* lpv = sm + 2 * K;
    float* l1m = sm + 3 * K;
    float* red = sm + 4 * K;       // 512 floats: eSum[256], bSum[256]

    const int l    = blockIdx.x;
    const int tid  = threadIdx.x;
    const int w    = tid >> 6;
    const int lane = tid & 63;

    if (tid < K) {
        const float* p = pred_poses + ((size_t)l * K + tid) * 3;
        px[tid] = p[0];
        py[tid] = p[1];
        float pv = fminf(fmaxf(p[2], EPS_BCE), 1.0f - EPS_BCE);
        lpv[tid] = logf(pv);
        l1m[tid] = logf(1.0f - pv);
    }
    __syncthreads();

    float eS = 0.0f, bS = 0.0f;
    if (lane < Lp) {
        const float  invDen = 1.0f / (2.0f * target_areas[lane] + EPS_AREA);
        const float* t = target_poses + (size_t)lane * K * 3;
        for (int k = w; k < K; k += 4) {
            float tx = t[3 * k + 0];
            float ty = t[3 * k + 1];
            float tv = t[3 * k + 2];
            float dx = px[k] - tx;
            float dy = py[k] - ty;
            float d2 = dx * dx + dy * dy;
            eS += __expf(-d2 * invDen);
            bS += fmaf(tv, lpv[k] - l1m[k], l1m[k]);
        }
    }
    red[tid]       = eS;
    red[256 + tid] = bS;
    __syncthreads();

    if (w == 0) {
        float eSum = red[lane] + red[64 + lane] + red[128 + lane] + red[192 + lane];
        float bSum = red[256 + lane] + red[320 + lane] + red[384 + lane] + red[448 + lane];
        float val = 0.0f;
        if (lane < Lp) {
            float tf = eSum / (float)K;
            float d  = pred_feedbacks[l] - tf;
            val = ious[(size_t)l * Lp + lane] * (d * d - bSum / (float)K);
        }
        for (int off = 32; off > 0; off >>= 1) val += __shfl_down(val, off, 64);
        if (lane == 0) partial[l] = val;
    }
}

// Generic fallback loss (any Lp): one wave per l, lp strided over lanes.
__global__ __launch_bounds__(64) void loss_partial1_kernel(
    const float* __restrict__ pred_poses, const float* __restrict__ target_poses,
    const float* __restrict__ pred_feedbacks, const float* __restrict__ ious,
    const float* __restrict__ target_areas, float* __restrict__ partial,
    int Lp, int K)
{
    extern __shared__ float sm[];
    float* px  = sm;
    float* py  = sm + K;
    float* lpv = sm + 2 * K;
    float* l1m = sm + 3 * K;

    const int l   = blockIdx.x;
    const int tid = threadIdx.x;
    if (tid < K) {
        const float* p = pred_poses + ((size_t)l * K + tid) * 3;
        px[tid] = p[0];
        py[tid] = p[1];
        float pv = fminf(fmaxf(p[2], EPS_BCE), 1.0f - EPS_BCE);
        lpv[tid] = logf(pv);
        l1m[tid] = logf(1.0f - pv);
    }
    __syncthreads();

    float acc = 0.0f;
    for (int lp = tid; lp < Lp; lp += 64) {
        const float  invDen = 1.0f / (2.0f * target_areas[lp] + EPS_AREA);
        const float* t = target_poses + (size_t)lp * K * 3;
        float eS = 0.0f, bS = 0.0f;
        for (int k = 0; k < K; ++k) {
            float dx = px[k] - t[3 * k + 0];
            float dy = py[k] - t[3 * k + 1];
            float tv = t[3 * k + 2];
            eS += __expf(-(dx * dx + dy * dy) * invDen);
            bS += fmaf(tv, lpv[k] - l1m[k], l1m[k]);
        }
        float d = pred_feedbacks[l] - eS / (float)K;
        acc += ious[(size_t)l * Lp + lp] * (d * d - bS / (float)K);
    }
    for (int off = 32; off > 0; off >>= 1) acc += __shfl_down(acc, off, 64);
    if (tid == 0) partial[l] = acc;
}

// Generic final reduce (fallback path only).
__global__ __launch_bounds__(256) void loss_reduce_kernel(
    const float* __restrict__ partial, float* __restrict__ loss_out, int L)
{
    __shared__ float wsum[4];
    float s = 0.0f;
    for (int i = threadIdx.x; i < L; i += 256) s += partial[i];
    for (int off = 32; off > 0; off >>= 1) s += __shfl_down(s, off, 64);
    if ((threadIdx.x & 63) == 0) wsum[threadIdx.x >> 6] = s;
    __syncthreads();
    if (threadIdx.x == 0) *loss_out = wsum[0] + wsum[1] + wsum[2] + wsum[3];
}

extern "C" void kernel_launch(void* const* d_in, const int* in_sizes, int n_in,
                              void* d_out, int out_size, void* d_ws, size_t ws_size,
                              hipStream_t stream) {
    const float* pred_poses     = (const float*)d_in[0];  // (L,K,3)
    const float* target_poses   = (const float*)d_in[1];  // (Lp,K,3)
    const float* pred_feedbacks = (const float*)d_in[2];  // (L,)
    const float* ious           = (const float*)d_in[3];  // (L,Lp)
    const float* target_areas   = (const float*)d_in[4];  // (Lp,)
    float* out = (float*)d_out;

    const int L  = in_sizes[2];                 // 512
    const int Lp = in_sizes[4];                 // 64
    const int K  = in_sizes[0] / (3 * L);       // 17

    const long rows   = (long)L * 3 * K;                  // 26112
    const long inner  = ((long)out_size - 1) / rows;      // fd*fd = 3136
    const int  inner4 = (int)(inner / 4);                 // 784
    const int  rem    = (int)(inner - (long)inner4 * 4);  // 0

    float* loss_slot = out + ((size_t)out_size - 1);
    float* partial   = (float*)d_ws;                      // L floats

    // ---- loss stage 1 first (broadcast kernel consumes partial[]) ----
    if (Lp <= 64) {
        const size_t smem = (4 * (size_t)K + 512) * sizeof(float);
        loss_partial4_kernel<<<L, 256, smem, stream>>>(
            pred_poses, target_poses, pred_feedbacks, ious, target_areas,
            partial, Lp, K);
    } else {
        const size_t smem = 4 * (size_t)K * sizeof(float);
        loss_partial1_kernel<<<L, 64, smem, stream>>>(
            pred_poses, target_poses, pred_feedbacks, ious, target_areas,
            partial, Lp, K);
    }

    if (inner4 == 784 && rem == 0) {
        const unsigned int total4 = (unsigned int)(rows * 784);
        broadcast_flat_kernel<784><<<4096, 256, 0, stream>>>(
            pred_poses, out, total4, partial, loss_slot, L);
    } else {
        broadcast_rows_kernel<<<(int)((rows + 3) / 4), 256, 0, stream>>>(
            pred_poses, out, (int)rows, inner, inner4);
        loss_reduce_kernel<<<1, 256, 0, stream>>>(partial, loss_slot, L);
    }
}